// Round 10
// baseline (33.825 us; speedup 1.0000x reference)
//
#include <hip/hip_runtime.h>
#include <cmath>

typedef __attribute__((ext_vector_type(8))) short short8;
typedef __attribute__((ext_vector_type(4))) float f32x4;

#define NB 32
#define MU_OUT_SZ (NB*100*64)   // 204800
#define LDAP 56                 // shorts per (h,w) cell in LDS (112 B padded)

__device__ inline unsigned short f2bf(float f) {
  unsigned u = __builtin_bit_cast(unsigned, f);
  u += 0x7fffu + ((u >> 16) & 1u);
  return (unsigned short)(u >> 16);
}

// ---------------- prepW: coalesced stage of w slice -> LDS -> fragment pack (proven) ----------------
__global__ __launch_bounds__(256) void prepW(
    const float* __restrict__ w_mu, const float* __restrict__ w_sigma,
    unsigned short* __restrict__ wf) {
  __shared__ float wsh[2048];              // this ij's 32 K-rows x 64 cols (8 KB)
  const int ij = blockIdx.x, t = threadIdx.x;
  const float4* src = (const float4*)(w_mu + (size_t)ij * 2048);
  ((float4*)wsh)[t]       = src[t];
  ((float4*)wsh)[t + 256] = src[t + 256];
  __syncthreads();
#pragma unroll
  for (int id0 = 0; id0 < 512; id0 += 256) {
    const int id = id0 + t;
    const int kind = id >> 8;              // 0: W, 1: W^2 + sp
    const int rest = id & 255;
    const int n = rest >> 6, l = rest & 63;
    const int col = n * 16 + (l & 15);     // output channel k
    const int m0 = (l >> 4) * 8;           // K-row base within this ij
    const float sp = log1pf(expf(w_sigma[col]));
    unsigned short v[8];
#pragma unroll
    for (int i = 0; i < 8; ++i) {
      const float wv = wsh[(m0 + i) * 64 + col];
      const float x = kind ? (wv * wv + sp) : wv;
      v[i] = f2bf(x);
    }
    uint4 pk;
    pk.x = v[0] | ((unsigned)v[1] << 16);
    pk.y = v[2] | ((unsigned)v[3] << 16);
    pk.z = v[4] | ((unsigned)v[5] << 16);
    pk.w = v[6] | ((unsigned)v[7] << 16);
    *(uint4*)(wf + (size_t)((ij * 8 + kind * 4 + n) * 64 + l) * 8) = pk;
  }
}

// ---------------- fusedH: per block = (r, q-half, b): G tiles + mu|dv + stream slab ----------------
__global__ __launch_bounds__(512) void fusedH(
    const float* __restrict__ mu_in, const float* __restrict__ Sigma_in,
    const unsigned short* __restrict__ wf, const float* __restrict__ w_sigma,
    float* __restrict__ out) {
  __shared__ unsigned short mu_sh[196 * LDAP];   // 21952 B
  __shared__ unsigned short sd_sh[196 * LDAP];   // 21952 B
  __shared__ float g_sh[16][64];                 // 4096 B (q-local)
  __shared__ float dv_sh[16][64];                // 4096 B
  const int r = blockIdx.x;            // p-row tile 0..6
  const int zh = blockIdx.y;           // q half: 0 -> [0,64), 1 -> [64,100)
  const int b = blockIdx.z;
  const int t = threadIdx.x, l = t & 63, w = t >> 6;
  const int p0 = r * 16;
  const bool hasDv = (zh == 0) ? (r <= 3) : (r >= 4);

  // ---- stage mu[b] (always) and diag(Sigma[b]) (only if hasDv) ----
  const float4* mu4 = (const float4*)(mu_in + (size_t)b * 6272);
  for (int f = t; f < 1568; f += 512) {
    const float4 v = mu4[f];
    const int row = f >> 3, c = (f & 7) * 4;
    ushort4 pv;
    pv.x = f2bf(v.x); pv.y = f2bf(v.y); pv.z = f2bf(v.z); pv.w = f2bf(v.w);
    *(ushort4*)(mu_sh + row * LDAP + c) = pv;
  }
  if (hasDv) {
    for (int f = t; f < 1568; f += 512) {
      const int row = f >> 3, c = (f & 7) * 4;
      const float4 s = *(const float4*)(Sigma_in +
          ((size_t)(b * 196 + row) * 196 + row) * 32 + c);
      ushort4 ps;
      ps.x = f2bf(s.x); ps.y = f2bf(s.y); ps.z = f2bf(s.z); ps.w = f2bf(s.w);
      *(ushort4*)(sd_sh + row * LDAP + c) = ps;
    }
  }
  __syncthreads();

  // ---- MFMA phase ----
  const int laneP = l & 15, g16 = (l >> 4) * 8;
  const int pA = (p0 + laneP > 99) ? 99 : p0 + laneP;
  const int baseA = ((pA / 10) * 14 + (pA % 10)) * LDAP + g16;
  // G-tile role: zh=0 -> waves 0..3 own tiles 0..3; zh=1 -> waves 0..2 own tiles 4..6
  const int gT = (zh == 0) ? ((w < 4) ? w : -1) : ((w < 3) ? 4 + w : -1);
  // secondary role (mu if !hasDv, dv if hasDv): zh=0 -> waves 4..7; zh=1 -> waves 3..6
  const int sn = (zh == 0) ? ((w >= 4) ? w - 4 : -1)
                           : ((w >= 3 && w < 7) ? w - 3 : -1);
  int qg = 0, baseB = 0;
  if (gT >= 0) {
    qg = gT * 16 + laneP;
    const int qc = qg > 99 ? 99 : qg;
    baseB = ((qc / 10) * 14 + (qc % 10)) * LDAP + g16;
  }
  const int kslot = (sn >= 0) ? (hasDv ? 4 + sn : sn) : 0;

  const short8* wfp = (const short8*)wf;
  short8 fw = {};
  if (sn >= 0) fw = wfp[(size_t)kslot * 64 + l];
  f32x4 aG = {}, aX = {};
  for (int ij = 0; ij < 25; ++ij) {
    short8 fw_n = fw;
    if (sn >= 0 && ij < 24) fw_n = wfp[(size_t)((ij + 1) * 8 + kslot) * 64 + l];
    const int off = ((ij / 5) * 14 + (ij % 5)) * LDAP;
    if (gT >= 0) {
      const short8 fA = *(const short8*)(mu_sh + baseA + off);
      const short8 fB = *(const short8*)(mu_sh + baseB + off);
      aG = __builtin_amdgcn_mfma_f32_16x16x32_bf16(fA, fB, aG, 0, 0, 0);
    }
    if (sn >= 0) {
      if (hasDv) {
        const short8 fS = *(const short8*)(sd_sh + baseA + off);
        aX = __builtin_amdgcn_mfma_f32_16x16x32_bf16(fS, fw, aX, 0, 0, 0);
      } else {
        const short8 fA = *(const short8*)(mu_sh + baseA + off);
        aX = __builtin_amdgcn_mfma_f32_16x16x32_bf16(fA, fw, aX, 0, 0, 0);
      }
    }
    fw = fw_n;
  }

  const int prow0 = (l >> 4) * 4;
  if (gT >= 0 && qg < 100) {
    const int ql = qg - zh * 64;         // local q within half
#pragma unroll
    for (int j = 0; j < 4; ++j) g_sh[prow0 + j][ql] = aG[j];
  }
  if (sn >= 0) {
    const int k = sn * 16 + laneP;
    if (hasDv) {
#pragma unroll
      for (int j = 0; j < 4; ++j) dv_sh[prow0 + j][k] = aX[j];
    } else {
      float* mo = out + (size_t)b * 6400;
#pragma unroll
      for (int j = 0; j < 4; ++j) {
        const int p = p0 + prow0 + j;
        if (p < 100) mo[p * 64 + k] = aX[j];
      }
    }
  }
  __syncthreads();

  // ---- write phase: slab = nrows x qspan x 64 ----
  const int nrows = (r == 6) ? 4 : 16;
  const int k4 = (t & 15) * 4;
  const float4 wsv = *(const float4*)(w_sigma + k4);
  f32x4 sp4;
  sp4.x = log1pf(expf(wsv.x));
  sp4.y = log1pf(expf(wsv.y));
  sp4.z = log1pf(expf(wsv.z));
  sp4.w = log1pf(expf(wsv.w));
  float* sig0 = out + MU_OUT_SZ + (size_t)(b * 100 + p0) * 6400 + zh * 64 * 64;

  if (zh == 0) {
    for (int row = 0; row < nrows; ++row) {
      const bool dvRow = hasDv && (p0 + row < 64);
      float* rowp = sig0 + (size_t)row * 6400;
#pragma unroll
      for (int s = 0; s < 2; ++s) {
        const int idx = t + s * 512;          // 0..1023
        const int ql = idx >> 4;              // q = ql (0..63)
        const float g = g_sh[row][ql];
        f32x4 v;
        v.x = sp4.x * g; v.y = sp4.y * g; v.z = sp4.z * g; v.w = sp4.w * g;
        if (dvRow && ql == p0 + row) {
          const float4 dvv = *(const float4*)&dv_sh[row][k4];
          v.x += dvv.x; v.y += dvv.y; v.z += dvv.z; v.w += dvv.w;
        }
        v.x = (ql == k4)     ? fabsf(v.x) : v.x;
        v.y = (ql == k4 + 1) ? fabsf(v.y) : v.y;
        v.z = (ql == k4 + 2) ? fabsf(v.z) : v.z;
        v.w = (ql == k4 + 3) ? fabsf(v.w) : v.w;
        __builtin_nontemporal_store(v, (f32x4*)(rowp + (size_t)idx * 4));
      }
    }
  } else {
    for (int row = 0; row < nrows; ++row) {
      float* rowp = sig0 + (size_t)row * 6400;
      for (int idx = t; idx < 576; idx += 512) { // 36 q * 16 f4
        const int ql = idx >> 4;              // q = 64 + ql
        const float g = g_sh[row][ql];
        f32x4 v;
        v.x = sp4.x * g; v.y = sp4.y * g; v.z = sp4.z * g; v.w = sp4.w * g;
        if (hasDv && 64 + ql == p0 + row) {
          const float4 dvv = *(const float4*)&dv_sh[row][k4];
          v.x += dvv.x; v.y += dvv.y; v.z += dvv.z; v.w += dvv.w;
        }
        // q >= 64 > k4+3 (<=63): abs never applies in this half
        __builtin_nontemporal_store(v, (f32x4*)(rowp + (size_t)idx * 4));
      }
    }
  }
}

extern "C" void kernel_launch(void* const* d_in, const int* in_sizes, int n_in,
                              void* d_out, int out_size, void* d_ws, size_t ws_size,
                              hipStream_t stream) {
  const float* mu_in    = (const float*)d_in[0];
  const float* Sigma_in = (const float*)d_in[1];
  const float* w_mu     = (const float*)d_in[2];
  const float* w_sigma  = (const float*)d_in[3];
  float* out = (float*)d_out;
  unsigned short* wf = (unsigned short*)d_ws;   // 204800 B

  prepW<<<25, 256, 0, stream>>>(w_mu, w_sigma, wf);
  fusedH<<<dim3(7, 2, NB), 512, 0, stream>>>(mu_in, Sigma_in, wf, w_sigma, out);
}

// Round 11
// 30.266 us; speedup vs baseline: 1.1176x; 1.1176x over previous
//
#include <hip/hip_runtime.h>
#include <cmath>

typedef __attribute__((ext_vector_type(8))) short short8;
typedef __attribute__((ext_vector_type(4))) float f32x4;

#define NB 32
#define MU_OUT_SZ (NB*100*64)   // 204800
#define LDAP 56                 // shorts per (h,w) cell in LDS (112 B padded)

__device__ inline unsigned short f2bf(float f) {
  unsigned u = __builtin_bit_cast(unsigned, f);
  u += 0x7fffu + ((u >> 16) & 1u);
  return (unsigned short)(u >> 16);
}

// ---------------- prepW: coalesced stage of w slice -> LDS -> fragment pack (proven) ----------------
__global__ __launch_bounds__(256) void prepW(
    const float* __restrict__ w_mu, const float* __restrict__ w_sigma,
    unsigned short* __restrict__ wf) {
  __shared__ float wsh[2048];              // this ij's 32 K-rows x 64 cols (8 KB)
  const int ij = blockIdx.x, t = threadIdx.x;
  const float4* src = (const float4*)(w_mu + (size_t)ij * 2048);
  ((float4*)wsh)[t]       = src[t];
  ((float4*)wsh)[t + 256] = src[t + 256];
  __syncthreads();
#pragma unroll
  for (int id0 = 0; id0 < 512; id0 += 256) {
    const int id = id0 + t;
    const int kind = id >> 8;              // 0: W, 1: W^2 + sp
    const int rest = id & 255;
    const int n = rest >> 6, l = rest & 63;
    const int col = n * 16 + (l & 15);     // output channel k
    const int m0 = (l >> 4) * 8;           // K-row base within this ij
    const float sp = log1pf(expf(w_sigma[col]));
    unsigned short v[8];
#pragma unroll
    for (int i = 0; i < 8; ++i) {
      const float wv = wsh[(m0 + i) * 64 + col];
      const float x = kind ? (wv * wv + sp) : wv;
      v[i] = f2bf(x);
    }
    uint4 pk;
    pk.x = v[0] | ((unsigned)v[1] << 16);
    pk.y = v[2] | ((unsigned)v[3] << 16);
    pk.z = v[4] | ((unsigned)v[5] << 16);
    pk.w = v[6] | ((unsigned)v[7] << 16);
    *(uint4*)(wf + (size_t)((ij * 8 + kind * 4 + n) * 64 + l) * 8) = pk;
  }
}

// ---------------- fusedK: gemm + LDS G/dv + direct Sigma_out stream (R9, plain stores) ----------------
__global__ __launch_bounds__(512) void fusedK(
    const float* __restrict__ mu_in, const float* __restrict__ Sigma_in,
    const unsigned short* __restrict__ wf, const float* __restrict__ w_sigma,
    float* __restrict__ out) {
  __shared__ unsigned short mu_sh[196 * LDAP];   // 21952 B
  __shared__ unsigned short sd_sh[196 * LDAP];   // 21952 B
  __shared__ float g_sh[16][100];                // 6400 B
  __shared__ float dv_sh[16][64];                // 4096 B
  const int r = blockIdx.x;            // p-row tile 0..6
  const int b = blockIdx.y;
  const int t = threadIdx.x, l = t & 63, w = t >> 6;

  // ---- stage mu[b] and diag(Sigma[b]) as bf16, padded rows ----
  const float4* mu4 = (const float4*)(mu_in + (size_t)b * 6272);
  for (int f = t; f < 1568; f += 512) {
    const float4 v = mu4[f];
    const int row = f >> 3, c = (f & 7) * 4;
    ushort4 pv;
    pv.x = f2bf(v.x); pv.y = f2bf(v.y); pv.z = f2bf(v.z); pv.w = f2bf(v.w);
    *(ushort4*)(mu_sh + row * LDAP + c) = pv;
    const float4 s = *(const float4*)(Sigma_in +
        ((size_t)(b * 196 + row) * 196 + row) * 32 + c);
    ushort4 ps;
    ps.x = f2bf(s.x); ps.y = f2bf(s.y); ps.z = f2bf(s.z); ps.w = f2bf(s.w);
    *(ushort4*)(sd_sh + row * LDAP + c) = ps;
  }
  __syncthreads();

  // ---- MFMA phase ----
  const int laneP = l & 15, g16 = (l >> 4) * 8;
  const int pA = (r * 16 + laneP > 99) ? 99 : r * 16 + laneP;
  const int baseA = ((pA / 10) * 14 + (pA % 10)) * LDAP + g16;
  const bool doG = (w < 7);
  const int q = w * 16 + laneP;                    // G col (waves 0..6)
  const int qc = q > 99 ? 99 : q;
  const int baseB = ((qc / 10) * 14 + (qc % 10)) * LDAP + g16;
  const bool doMu = (w < 4);
  const int n = doMu ? w : (w - 4);                // k-tile
  const int kslot = doMu ? n : (4 + n);            // wf tile index

  const short8* wfp = (const short8*)wf;           // [(ij*8 + kslot)*64 + l]
  short8 fw = wfp[(size_t)kslot * 64 + l];         // prefetch ij=0
  f32x4 aG = {}, aX = {};
  for (int ij = 0; ij < 25; ++ij) {
    const short8 fw_n = (ij < 24) ? wfp[(size_t)((ij + 1) * 8 + kslot) * 64 + l] : fw;
    const int off = ((ij / 5) * 14 + (ij % 5)) * LDAP;
    if (doG) {
      const short8 fA = *(const short8*)(mu_sh + baseA + off);
      const short8 fB = *(const short8*)(mu_sh + baseB + off);
      aG = __builtin_amdgcn_mfma_f32_16x16x32_bf16(fA, fB, aG, 0, 0, 0);
      if (doMu) {
        aX = __builtin_amdgcn_mfma_f32_16x16x32_bf16(fA, fw, aX, 0, 0, 0);
      } else {
        const short8 fS = *(const short8*)(sd_sh + baseA + off);
        aX = __builtin_amdgcn_mfma_f32_16x16x32_bf16(fS, fw, aX, 0, 0, 0);
      }
    } else {
      const short8 fS = *(const short8*)(sd_sh + baseA + off);
      aX = __builtin_amdgcn_mfma_f32_16x16x32_bf16(fS, fw, aX, 0, 0, 0);
    }
    fw = fw_n;
  }

  const int prow0 = (l >> 4) * 4;
  if (doG && q < 100) {
#pragma unroll
    for (int j = 0; j < 4; ++j) g_sh[prow0 + j][q] = aG[j];
  }
  const int k = n * 16 + laneP;
  if (doMu) {
    float* mo = out + (size_t)b * 6400;
#pragma unroll
    for (int j = 0; j < 4; ++j) {
      const int p = r * 16 + prow0 + j;
      if (p < 100) mo[p * 64 + k] = aX[j];
    }
  } else {
#pragma unroll
    for (int j = 0; j < 4; ++j) dv_sh[prow0 + j][k] = aX[j];
  }
  __syncthreads();

  // ---- write phase: stream Sigma_out rows [16r, 16r+nrows) of batch b ----
  const int nrows = (r == 6) ? 4 : 16;
  const int p0 = r * 16;
  const int k4 = (t & 15) * 4;         // constant per thread (512 % 16 == 0)
  const float4 wsv = *(const float4*)(w_sigma + k4);
  f32x4 sp4;
  sp4.x = log1pf(expf(wsv.x));
  sp4.y = log1pf(expf(wsv.y));
  sp4.z = log1pf(expf(wsv.z));
  sp4.w = log1pf(expf(wsv.w));
  float* sig = out + MU_OUT_SZ + ((size_t)(b * 100 + p0) * 100) * 64;
  const int total = nrows * 1600;      // nrows * 100q * 16 float4
  for (int l4 = t; l4 < total; l4 += 512) {
    const int row = l4 / 1600;
    const int rem = l4 - row * 1600;
    const int qq = rem >> 4;
    const float g = g_sh[row][qq];
    f32x4 v;
    v.x = sp4.x * g; v.y = sp4.y * g; v.z = sp4.z * g; v.w = sp4.w * g;
    if (qq == p0 + row) {
      const float4 dvv = *(const float4*)&dv_sh[row][k4];
      v.x += dvv.x; v.y += dvv.y; v.z += dvv.z; v.w += dvv.w;
    }
    v.x = (qq == k4)     ? fabsf(v.x) : v.x;
    v.y = (qq == k4 + 1) ? fabsf(v.y) : v.y;
    v.z = (qq == k4 + 2) ? fabsf(v.z) : v.z;
    v.w = (qq == k4 + 3) ? fabsf(v.w) : v.w;
    *(f32x4*)(sig + (size_t)l4 * 4) = v;   // plain store: let MALL absorb the burst
  }
}

extern "C" void kernel_launch(void* const* d_in, const int* in_sizes, int n_in,
                              void* d_out, int out_size, void* d_ws, size_t ws_size,
                              hipStream_t stream) {
  const float* mu_in    = (const float*)d_in[0];
  const float* Sigma_in = (const float*)d_in[1];
  const float* w_mu     = (const float*)d_in[2];
  const float* w_sigma  = (const float*)d_in[3];
  float* out = (float*)d_out;
  unsigned short* wf = (unsigned short*)d_ws;   // 204800 B

  prepW<<<25, 256, 0, stream>>>(w_mu, w_sigma, wf);
  fusedK<<<dim3(7, NB), 512, 0, stream>>>(mu_in, Sigma_in, wf, w_sigma, out);
}